// Round 1
// baseline (1034.251 us; speedup 1.0000x reference)
//
#include <hip/hip_runtime.h>
#include <math.h>

#define TEMP 0.07f
#define CSHIFT (1.0f / 0.07f)
#define MAXM 8

__device__ __forceinline__ int lower_bound_i(const int* a, int n, int v) {
    int lo = 0, hi = n;
    while (lo < hi) { int mid = (lo + hi) >> 1; if (a[mid] < v) lo = mid + 1; else hi = mid; }
    return lo;
}
__device__ __forceinline__ int upper_bound_i(const int* a, int n, int v) {
    int lo = 0, hi = n;
    while (lo < hi) { int mid = (lo + hi) >> 1; if (a[mid] <= v) lo = mid + 1; else hi = mid; }
    return lo;
}

// ---------------- kernel 1: per-row inverse L2 norms ----------------
__global__ void k_norms(const float* __restrict__ fb, const float* __restrict__ fd,
                        int Nb, int Nd, int D,
                        float* __restrict__ invb, float* __restrict__ invd) {
    int gw = (blockIdx.x * blockDim.x + threadIdx.x) >> 6;  // global wave id
    int lane = threadIdx.x & 63;
    if (gw >= Nb + Nd) return;
    const float* row;
    float* out;
    if (gw < Nb) { row = fb + (size_t)gw * D; out = invb + gw; }
    else         { row = fd + (size_t)(gw - Nb) * D; out = invd + (gw - Nb); }
    float s = 0.f;
    for (int d = lane * 4; d < D; d += 256) {
        float4 v = *(const float4*)(row + d);
        s += v.x * v.x + v.y * v.y + v.z * v.z + v.w * v.w;
    }
    #pragma unroll
    for (int m = 32; m >= 1; m >>= 1) s += __shfl_xor(s, m, 64);
    if (lane == 0) *out = rsqrtf(s);
}

// ---------------- kernel 2: metadata (single block) ----------------
__global__ void k_meta(const int* __restrict__ td, const int* __restrict__ bd,
                       const int* __restrict__ im, const int* __restrict__ ut,
                       int Nd, int G, int Nb,
                       int* __restrict__ mouth_word, int* __restrict__ group_batch,
                       int* __restrict__ group_is_mouth,
                       int* __restrict__ g_start, int* __restrict__ g_cnt) {
    int t = threadIdx.x;
    for (int i = t; i < Nb; i += blockDim.x) mouth_word[i] = -1;
    for (int g = t; g < G; g += blockDim.x) { group_batch[g] = -1; group_is_mouth[g] = -1; }
    __syncthreads();
    for (int j = t; j < Nd; j += blockDim.x) {
        int g = lower_bound_i(ut, G, td[j]);
        atomicMax(&group_batch[g], bd[j]);
        atomicMax(&group_is_mouth[g], im[j]);
        if (im[j] == 1) atomicMax(&mouth_word[bd[j]], td[j]);
    }
    for (int g = t; g < G; g += blockDim.x) {
        int s = lower_bound_i(td, Nd, ut[g]);
        int e = upper_bound_i(td, Nd, ut[g]);
        g_start[g] = s;
        g_cnt[g] = e - s;
    }
}

// ---------------- kernel 3: main accumulation ----------------
// grid: (G groups) x (row chunks). block = 256 threads = 4 waves.
__global__ void k_main(const float* __restrict__ fb, const float* __restrict__ fd,
                       const int* __restrict__ tb, const int* __restrict__ bb_arr,
                       const int* __restrict__ bd, const int* __restrict__ ut,
                       const float* __restrict__ invb, const float* __restrict__ invd,
                       const int* __restrict__ mouth_word, const int* __restrict__ group_batch,
                       const int* __restrict__ group_is_mouth,
                       const int* __restrict__ g_start, const int* __restrict__ g_cnt,
                       int Nb, int D, int rows_per_blk,
                       float* __restrict__ rowsumA, float* __restrict__ numv,
                       float* __restrict__ t1v, float* __restrict__ t3v) {
    extern __shared__ float smem[];           // sd[MAXM][D] then int bd_s[MAXM]
    float* sd = smem;
    int* bd_s = (int*)(smem + MAXM * D);
    __shared__ float redsm[3][8];

    int g = blockIdx.x;
    int ic = blockIdx.y;
    int i0 = ic * rows_per_blk;
    int i1 = i0 + rows_per_blk;
    if (i1 > Nb) i1 = Nb;

    int start = g_start[g], cnt = g_cnt[g];
    int t = threadIdx.x, lane = t & 63, wid = t >> 6;
    int nwaves = blockDim.x >> 6;
    int gcol = ut[g];
    int gb = group_batch[g], gm = group_is_mouth[g];

    float num_w = 0.f, t1_w = 0.f, t3_w = 0.f;

    for (int cb = 0; cb < cnt; cb += MAXM) {
        int cc = cnt - cb; if (cc > MAXM) cc = MAXM;
        __syncthreads();
        for (int c = 0; c < cc; ++c) {
            int j = start + cb + c;
            float inv = invd[j];
            for (int d = t; d < D; d += blockDim.x) sd[c * D + d] = fd[(size_t)j * D + d] * inv;
            if (t == 0) bd_s[c] = bd[j];
        }
        __syncthreads();

        for (int i = i0 + wid; i < i1; i += nwaves) {
            float dot[MAXM];
            #pragma unroll
            for (int c = 0; c < MAXM; ++c) dot[c] = 0.f;

            for (int d = lane * 4; d < D; d += 256) {
                float4 v = *(const float4*)(fb + (size_t)i * D + d);
                #pragma unroll
                for (int c = 0; c < MAXM; ++c) {
                    if (c < cc) {
                        float4 w = *(const float4*)(sd + c * D + d);
                        dot[c] += v.x * w.x + v.y * w.y + v.z * w.z + v.w * w.w;
                    }
                }
            }
            #pragma unroll
            for (int m = 32; m >= 1; m >>= 1) {
                #pragma unroll
                for (int c = 0; c < MAXM; ++c) {
                    if (c < cc) dot[c] += __shfl_xor(dot[c], m, 64);
                }
            }

            // wave-uniform tail (all lanes compute identical values)
            int tbi = tb[i], bbi = bb_arr[i];
            bool is_fg = (tbi != -1);
            int mw = mouth_word[bbi];
            bool match = is_fg ? (gcol == mw) : ((gb == bbi) && (gm == 0));
            float scale = invb[i] * (1.0f / TEMP);
            float sumE = 0.f, sumA = 0.f;
            #pragma unroll
            for (int c = 0; c < MAXM; ++c) {
                if (c < cc) {
                    float e = __expf(dot[c] * scale - CSHIFT);
                    sumE += e;
                    bool zero = match && (bbi != bd_s[c]);
                    sumA += zero ? 0.f : e;
                }
            }
            t1_w += sumA;
            if (match) { num_w += sumE; t3_w += sumA; }
            if (lane == 0) atomicAdd(&rowsumA[i], sumA);
        }
    }

    if (lane == 0) { redsm[0][wid] = num_w; redsm[1][wid] = t1_w; redsm[2][wid] = t3_w; }
    __syncthreads();
    if (t == 0) {
        float n = 0.f, a = 0.f, b = 0.f;
        for (int w = 0; w < nwaves; ++w) { n += redsm[0][w]; a += redsm[1][w]; b += redsm[2][w]; }
        atomicAdd(&numv[g], n);
        atomicAdd(&t1v[g], a);
        atomicAdd(&t3v[g], b);
    }
}

// ---------------- kernel 4: t2 scatter ----------------
__global__ void k_t2(const int* __restrict__ tb, const int* __restrict__ bb_arr,
                     const int* __restrict__ mouth_word, const int* __restrict__ ut,
                     const int* __restrict__ group_batch, const int* __restrict__ group_is_mouth,
                     const float* __restrict__ rowsumA, int Nb, int G,
                     float* __restrict__ t2v) {
    int i = blockIdx.x * blockDim.x + threadIdx.x;
    if (i >= Nb) return;
    float r = rowsumA[i];
    int tbi = tb[i], bbi = bb_arr[i];
    if (tbi != -1) {
        int mw = mouth_word[bbi];
        int g = lower_bound_i(ut, G, mw);
        atomicAdd(&t2v[g], r);
    } else {
        for (int g = 0; g < G; ++g) {
            if (group_batch[g] == bbi && group_is_mouth[g] == 0) atomicAdd(&t2v[g], r);
        }
    }
}

// ---------------- kernel 5: final reduction ----------------
__global__ void k_final(const float* __restrict__ numv, const float* __restrict__ t1v,
                        const float* __restrict__ t3v, const float* __restrict__ t2v,
                        int G, float* __restrict__ out) {
    __shared__ float s[256];
    int t = threadIdx.x;
    float acc = 0.f;
    for (int g = t; g < G; g += blockDim.x) {
        float den = t1v[g] + t2v[g] - t3v[g];
        acc += logf(den) - logf(numv[g]);
    }
    s[t] = acc;
    __syncthreads();
    for (int k = 128; k >= 1; k >>= 1) {
        if (t < k) s[t] += s[t + k];
        __syncthreads();
    }
    if (t == 0) out[0] = s[0] / (float)G;
}

extern "C" void kernel_launch(void* const* d_in, const int* in_sizes, int n_in,
                              void* d_out, int out_size, void* d_ws, size_t ws_size,
                              hipStream_t stream) {
    const float* fb = (const float*)d_in[0];
    const float* fd = (const float*)d_in[1];
    const int* tb = (const int*)d_in[2];
    const int* td = (const int*)d_in[3];
    const int* bb = (const int*)d_in[4];
    const int* bd = (const int*)d_in[5];
    const int* im = (const int*)d_in[6];
    const int* ut = (const int*)d_in[7];

    int Nb = in_sizes[2];
    int Nd = in_sizes[3];
    int G  = in_sizes[7];
    int D  = in_sizes[0] / Nb;
    float* out = (float*)d_out;

    float* ws = (float*)d_ws;
    float* invb = ws;      ws += Nb;
    float* invd = ws;      ws += Nd;
    float* rowsumA = ws;   float* zero_base = ws; ws += Nb;
    float* numv = ws;      ws += G;
    float* t1v = ws;       ws += G;
    float* t3v = ws;       ws += G;
    float* t2v = ws;       ws += G;
    int* iw = (int*)ws;
    int* mouth_word = iw;     iw += Nb;   // sized Nb (>= n_batches) for safety
    int* group_batch = iw;    iw += G;
    int* group_is_mouth = iw; iw += G;
    int* g_start = iw;        iw += G;
    int* g_cnt = iw;          iw += G;

    // zero all accumulators (ws is poisoned 0xAA and never re-poisoned)
    hipMemsetAsync(zero_base, 0, (size_t)(Nb + 4 * G) * sizeof(float), stream);

    {
        int waves = Nb + Nd;
        int blocks = (waves + 3) / 4;
        k_norms<<<blocks, 256, 0, stream>>>(fb, fd, Nb, Nd, D, invb, invd);
    }

    k_meta<<<1, 256, 0, stream>>>(td, bd, im, ut, Nd, G, Nb,
                                  mouth_word, group_batch, group_is_mouth, g_start, g_cnt);

    int rows_per_blk = 512;
    int ich = (Nb + rows_per_blk - 1) / rows_per_blk;
    dim3 grid(G, ich);
    size_t shm = (size_t)MAXM * D * sizeof(float) + MAXM * sizeof(int);
    k_main<<<grid, 256, shm, stream>>>(fb, fd, tb, bb, bd, ut, invb, invd,
                                       mouth_word, group_batch, group_is_mouth,
                                       g_start, g_cnt, Nb, D, rows_per_blk,
                                       rowsumA, numv, t1v, t3v);

    k_t2<<<(Nb + 255) / 256, 256, 0, stream>>>(tb, bb, mouth_word, ut, group_batch,
                                               group_is_mouth, rowsumA, Nb, G, t2v);

    k_final<<<1, 256, 0, stream>>>(numv, t1v, t3v, t2v, G, out);
}

// Round 2
// 172.350 us; speedup vs baseline: 6.0009x; 6.0009x over previous
//
#include <hip/hip_runtime.h>
#include <math.h>

#define TEMP 0.07f
#define CSHIFT (1.0f / 0.07f)

#define BM 128
#define BN 64
#define BK 64
#define TM 8
#define TN 4
#define BKP (BK + 4)   // padded k-stride: keeps 16B row alignment, spreads banks

__device__ __forceinline__ int lower_bound_i(const int* a, int n, int v) {
    int lo = 0, hi = n;
    while (lo < hi) { int mid = (lo + hi) >> 1; if (a[mid] < v) lo = mid + 1; else hi = mid; }
    return lo;
}

// ---------------- kernel 1: per-row inverse L2 norms ----------------
__global__ void k_norms(const float* __restrict__ fb, const float* __restrict__ fd,
                        int Nb, int Nd, int D,
                        float* __restrict__ invb, float* __restrict__ invd) {
    int gw = (blockIdx.x * blockDim.x + threadIdx.x) >> 6;
    int lane = threadIdx.x & 63;
    if (gw >= Nb + Nd) return;
    const float* row;
    float* out;
    if (gw < Nb) { row = fb + (size_t)gw * D; out = invb + gw; }
    else         { row = fd + (size_t)(gw - Nb) * D; out = invd + (gw - Nb); }
    float s = 0.f;
    for (int d = lane * 4; d < D; d += 256) {
        float4 v = *(const float4*)(row + d);
        s += v.x * v.x + v.y * v.y + v.z * v.z + v.w * v.w;
    }
    #pragma unroll
    for (int m = 32; m >= 1; m >>= 1) s += __shfl_xor(s, m, 64);
    if (lane == 0) *out = rsqrtf(s);
}

// ---------------- kernel 2: metadata (single block) ----------------
__global__ void k_meta(const int* __restrict__ td, const int* __restrict__ bd,
                       const int* __restrict__ im, const int* __restrict__ ut,
                       int Nd, int G, int Nb,
                       int* __restrict__ mouth_word, int* __restrict__ group_batch,
                       int* __restrict__ group_is_mouth,
                       int* __restrict__ col_g, int* __restrict__ col_gb,
                       int* __restrict__ col_gm, int* __restrict__ col_gc) {
    int t = threadIdx.x;
    for (int i = t; i < Nb; i += blockDim.x) mouth_word[i] = -1;
    for (int g = t; g < G; g += blockDim.x) { group_batch[g] = -1; group_is_mouth[g] = -1; }
    __syncthreads();
    for (int j = t; j < Nd; j += blockDim.x) {
        int g = lower_bound_i(ut, G, td[j]);
        col_g[j] = g;
        atomicMax(&group_batch[g], bd[j]);
        atomicMax(&group_is_mouth[g], im[j]);
        if (im[j] == 1) atomicMax(&mouth_word[bd[j]], td[j]);
    }
    __syncthreads();
    for (int j = t; j < Nd; j += blockDim.x) {
        int g = col_g[j];
        col_gb[j] = group_batch[g];
        col_gm[j] = group_is_mouth[g];
        col_gc[j] = ut[g];
    }
}

// ---------------- kernel 3: fused GEMM + epilogue ----------------
// grid: (Nb/BM) x (Nd/BN), 256 threads (4 waves), 8x4 strided micro-tile.
__global__ __launch_bounds__(256, 2)
void k_main(const float* __restrict__ fb, const float* __restrict__ fd,
            const int* __restrict__ tb, const int* __restrict__ bb_arr,
            const float* __restrict__ invb, const float* __restrict__ invd,
            const int* __restrict__ mouth_word,
            const int* __restrict__ col_g, const int* __restrict__ col_gb,
            const int* __restrict__ col_gm, const int* __restrict__ col_gc,
            int Nb, int Nd, int D,
            float* __restrict__ rowsumA, float* __restrict__ numv,
            float* __restrict__ t1v, float* __restrict__ t3v) {
    __shared__ float As[BM][BKP];
    __shared__ float Bs[BN][BKP];
    __shared__ float cnum[BN], ct1[BN], ct3[BN], rsum[BM];

    int bm = blockIdx.x * BM;
    int bn = blockIdx.y * BN;
    int t = threadIdx.x;
    int tx = t & 15, ty = t >> 4;

    float acc[TM][TN];
    #pragma unroll
    for (int mi = 0; mi < TM; ++mi)
        #pragma unroll
        for (int ni = 0; ni < TN; ++ni) acc[mi][ni] = 0.f;

    for (int k0 = 0; k0 < D; k0 += BK) {
        __syncthreads();
        // stage A: BM x BK floats = 2048 float4 / 256 thr = 8 each, coalesced
        #pragma unroll
        for (int s = 0; s < (BM * BK) / (256 * 4); ++s) {
            int idx = s * 256 + t;
            int r = idx >> 4;          // 0..127
            int c = idx & 15;          // float4 slot in k
            float4 v = *(const float4*)(fb + (size_t)(bm + r) * D + k0 + c * 4);
            *(float4*)&As[r][c * 4] = v;
        }
        // stage B (x invd): BN x BK = 1024 float4 / 256 = 4 each
        #pragma unroll
        for (int s = 0; s < (BN * BK) / (256 * 4); ++s) {
            int idx = s * 256 + t;
            int r = idx >> 4;
            int c = idx & 15;
            float inv = invd[bn + r];
            float4 v = *(const float4*)(fd + (size_t)(bn + r) * D + k0 + c * 4);
            v.x *= inv; v.y *= inv; v.z *= inv; v.w *= inv;
            *(float4*)&Bs[r][c * 4] = v;
        }
        __syncthreads();

        #pragma unroll 4
        for (int k = 0; k < BK; k += 4) {
            float4 a[TM], b[TN];
            #pragma unroll
            for (int mi = 0; mi < TM; ++mi) a[mi] = *(const float4*)&As[ty + 16 * mi][k];
            #pragma unroll
            for (int ni = 0; ni < TN; ++ni) b[ni] = *(const float4*)&Bs[tx + 16 * ni][k];
            #pragma unroll
            for (int mi = 0; mi < TM; ++mi)
                #pragma unroll
                for (int ni = 0; ni < TN; ++ni)
                    acc[mi][ni] += a[mi].x * b[ni].x + a[mi].y * b[ni].y
                                 + a[mi].z * b[ni].z + a[mi].w * b[ni].w;
        }
    }

    // ---- fused epilogue: element-wise exp + match masks, additive reductions ----
    // per-col meta (4 cols per thread)
    int cgb[TN], cgm[TN], cgc[TN];
    #pragma unroll
    for (int ni = 0; ni < TN; ++ni) {
        int col = bn + tx + 16 * ni;
        cgb[ni] = col_gb[col]; cgm[ni] = col_gm[col]; cgc[ni] = col_gc[col];
    }
    float pnum[TN], pt1[TN], pt3[TN], prow[TM];
    #pragma unroll
    for (int ni = 0; ni < TN; ++ni) { pnum[ni] = 0.f; pt1[ni] = 0.f; pt3[ni] = 0.f; }

    #pragma unroll
    for (int mi = 0; mi < TM; ++mi) {
        int i = bm + ty + 16 * mi;
        int tbi = tb[i], bbi = bb_arr[i];
        float sc = invb[i] * (1.0f / TEMP);
        int mw = mouth_word[bbi];
        bool is_fg = (tbi != -1);
        float pr = 0.f;
        #pragma unroll
        for (int ni = 0; ni < TN; ++ni) {
            float e = __expf(acc[mi][ni] * sc - CSHIFT);
            bool match = is_fg ? (cgc[ni] == mw) : ((cgb[ni] == bbi) && (cgm[ni] == 0));
            float a = (match && (bbi != cgb[ni])) ? 0.f : e;
            pnum[ni] += match ? e : 0.f;
            pt1[ni] += a;
            pt3[ni] += match ? a : 0.f;
            pr += a;
        }
        prow[mi] = pr;
    }

    // LDS reduction
    if (t < BN) { cnum[t] = 0.f; ct1[t] = 0.f; ct3[t] = 0.f; }
    if (t < BM) rsum[t] = 0.f;
    __syncthreads();
    #pragma unroll
    for (int ni = 0; ni < TN; ++ni) {
        int c = tx + 16 * ni;
        atomicAdd(&cnum[c], pnum[ni]);
        atomicAdd(&ct1[c], pt1[ni]);
        atomicAdd(&ct3[c], pt3[ni]);
    }
    #pragma unroll
    for (int mi = 0; mi < TM; ++mi) atomicAdd(&rsum[ty + 16 * mi], prow[mi]);
    __syncthreads();

    if (t < BN) {
        int g = col_g[bn + t];
        atomicAdd(&numv[g], cnum[t]);
        atomicAdd(&t1v[g], ct1[t]);
        atomicAdd(&t3v[g], ct3[t]);
    }
    if (t < BM) atomicAdd(&rowsumA[bm + t], rsum[t]);
}

// ---------------- kernel 4: t2 scatter ----------------
__global__ void k_t2(const int* __restrict__ tb, const int* __restrict__ bb_arr,
                     const int* __restrict__ mouth_word, const int* __restrict__ ut,
                     const int* __restrict__ group_batch, const int* __restrict__ group_is_mouth,
                     const float* __restrict__ rowsumA, int Nb, int G,
                     float* __restrict__ t2v) {
    int i = blockIdx.x * blockDim.x + threadIdx.x;
    if (i >= Nb) return;
    float r = rowsumA[i];
    int tbi = tb[i], bbi = bb_arr[i];
    if (tbi != -1) {
        int mw = mouth_word[bbi];
        int g = lower_bound_i(ut, G, mw);
        atomicAdd(&t2v[g], r);
    } else {
        for (int g = 0; g < G; ++g) {
            if (group_batch[g] == bbi && group_is_mouth[g] == 0) atomicAdd(&t2v[g], r);
        }
    }
}

// ---------------- kernel 5: final reduction ----------------
__global__ void k_final(const float* __restrict__ numv, const float* __restrict__ t1v,
                        const float* __restrict__ t3v, const float* __restrict__ t2v,
                        int G, float* __restrict__ out) {
    __shared__ float s[256];
    int t = threadIdx.x;
    float acc = 0.f;
    for (int g = t; g < G; g += blockDim.x) {
        float den = t1v[g] + t2v[g] - t3v[g];
        acc += logf(den) - logf(numv[g]);
    }
    s[t] = acc;
    __syncthreads();
    for (int k = 128; k >= 1; k >>= 1) {
        if (t < k) s[t] += s[t + k];
        __syncthreads();
    }
    if (t == 0) out[0] = s[0] / (float)G;
}

extern "C" void kernel_launch(void* const* d_in, const int* in_sizes, int n_in,
                              void* d_out, int out_size, void* d_ws, size_t ws_size,
                              hipStream_t stream) {
    const float* fb = (const float*)d_in[0];
    const float* fd = (const float*)d_in[1];
    const int* tb = (const int*)d_in[2];
    const int* td = (const int*)d_in[3];
    const int* bb = (const int*)d_in[4];
    const int* bd = (const int*)d_in[5];
    const int* im = (const int*)d_in[6];
    const int* ut = (const int*)d_in[7];

    int Nb = in_sizes[2];
    int Nd = in_sizes[3];
    int G  = in_sizes[7];
    int D  = in_sizes[0] / Nb;
    float* out = (float*)d_out;

    float* ws = (float*)d_ws;
    float* invb = ws;      ws += Nb;
    float* invd = ws;      ws += Nd;
    float* rowsumA = ws;   float* zero_base = ws; ws += Nb;
    float* numv = ws;      ws += G;
    float* t1v = ws;       ws += G;
    float* t3v = ws;       ws += G;
    float* t2v = ws;       ws += G;
    int* iw = (int*)ws;
    int* mouth_word = iw;     iw += Nb;
    int* group_batch = iw;    iw += G;
    int* group_is_mouth = iw; iw += G;
    int* col_g = iw;          iw += Nd;
    int* col_gb = iw;         iw += Nd;
    int* col_gm = iw;         iw += Nd;
    int* col_gc = iw;         iw += Nd;

    // zero accumulators (rowsumA, numv, t1v, t3v, t2v)
    hipMemsetAsync(zero_base, 0, (size_t)(Nb + 4 * G) * sizeof(float), stream);

    {
        int waves = Nb + Nd;
        int blocks = (waves + 3) / 4;
        k_norms<<<blocks, 256, 0, stream>>>(fb, fd, Nb, Nd, D, invb, invd);
    }

    k_meta<<<1, 256, 0, stream>>>(td, bd, im, ut, Nd, G, Nb,
                                  mouth_word, group_batch, group_is_mouth,
                                  col_g, col_gb, col_gm, col_gc);

    dim3 grid(Nb / BM, Nd / BN);
    k_main<<<grid, 256, 0, stream>>>(fb, fd, tb, bb, invb, invd, mouth_word,
                                     col_g, col_gb, col_gm, col_gc,
                                     Nb, Nd, D, rowsumA, numv, t1v, t3v);

    k_t2<<<(Nb + 255) / 256, 256, 0, stream>>>(tb, bb, mouth_word, ut, group_batch,
                                               group_is_mouth, rowsumA, Nb, G, t2v);

    k_final<<<1, 256, 0, stream>>>(numv, t1v, t3v, t2v, G, out);
}

// Round 3
// 73.100 us; speedup vs baseline: 14.1485x; 2.3577x over previous
//
#include <hip/hip_runtime.h>
#include <math.h>

#define TEMP 0.07f
#define INVT (1.0f / 0.07f)
#define CSHIFT (1.0f / 0.07f)

using bf16x8 = __attribute__((ext_vector_type(8))) short;
using f32x4  = __attribute__((ext_vector_type(4))) float;

__device__ __forceinline__ int lower_bound_i(const int* a, int n, int v) {
    int lo = 0, hi = n;
    while (lo < hi) { int mid = (lo + hi) >> 1; if (a[mid] < v) lo = mid + 1; else hi = mid; }
    return lo;
}

__device__ __forceinline__ unsigned short f2bf(float x) {
    unsigned int u = __float_as_uint(x);
    unsigned int r = (u + 0x7fffu + ((u >> 16) & 1u)) >> 16;   // RNE
    return (unsigned short)r;
}

// ---------------- kernel 1: normalize + bf16 convert + meta (block 0) ----------------
__global__ void k_prep(const float* __restrict__ fb, const float* __restrict__ fd,
                       int Nb, int Nd, int D,
                       unsigned short* __restrict__ fbh, unsigned short* __restrict__ fdh,
                       float* __restrict__ rowsumA,
                       const int* __restrict__ td, const int* __restrict__ bd,
                       const int* __restrict__ im, const int* __restrict__ ut, int G,
                       int* __restrict__ mouth_word, int* __restrict__ group_batch,
                       int* __restrict__ group_is_mouth,
                       int* __restrict__ col_g, int* __restrict__ col_gb,
                       int* __restrict__ col_gm, int* __restrict__ col_gc,
                       float* __restrict__ numv, float* __restrict__ t1v,
                       float* __restrict__ t3v) {
    int gw = (blockIdx.x * blockDim.x + threadIdx.x) >> 6;
    int lane = threadIdx.x & 63;
    if (gw < Nb + Nd) {
        const float* row; unsigned short* orow;
        if (gw < Nb) {
            row = fb + (size_t)gw * D; orow = fbh + (size_t)gw * D;
            if (lane == 0) rowsumA[gw] = 0.f;
        } else {
            row = fd + (size_t)(gw - Nb) * D; orow = fdh + (size_t)(gw - Nb) * D;
        }
        float s = 0.f;
        for (int d = lane * 4; d < D; d += 256) {
            float4 v = *(const float4*)(row + d);
            s += v.x * v.x + v.y * v.y + v.z * v.z + v.w * v.w;
        }
        #pragma unroll
        for (int m = 32; m >= 1; m >>= 1) s += __shfl_xor(s, m, 64);
        float inv = rsqrtf(s);
        for (int d = lane * 4; d < D; d += 256) {
            float4 v = *(const float4*)(row + d);
            ushort4 o;
            o.x = f2bf(v.x * inv); o.y = f2bf(v.y * inv);
            o.z = f2bf(v.z * inv); o.w = f2bf(v.w * inv);
            *(ushort4*)(orow + d) = o;
        }
    }
    if (blockIdx.x == 0) {
        int t = threadIdx.x;
        for (int i = t; i < Nb; i += blockDim.x) mouth_word[i] = -1;
        for (int g = t; g < G; g += blockDim.x) {
            group_batch[g] = -1; group_is_mouth[g] = -1;
            numv[g] = 0.f; t1v[g] = 0.f; t3v[g] = 0.f;
        }
        __syncthreads();
        for (int j = t; j < Nd; j += blockDim.x) {
            int g = lower_bound_i(ut, G, td[j]);
            col_g[j] = g;
            atomicMax(&group_batch[g], bd[j]);
            atomicMax(&group_is_mouth[g], im[j]);
            if (im[j] == 1) atomicMax(&mouth_word[bd[j]], td[j]);
        }
        __syncthreads();
        for (int j = t; j < Nd; j += blockDim.x) {
            int g = col_g[j];
            col_gb[j] = group_batch[g];
            col_gm[j] = group_is_mouth[g];
            col_gc[j] = ut[g];
        }
    }
}

// ---------------- kernel 2: MFMA GEMM + fused epilogue ----------------
// grid (Nb/64, Nd/64), 256 threads = 4 waves (2x2), each wave a 32x32 tile (2x2 frags).
__global__ __launch_bounds__(256, 4)
void k_main(const unsigned short* __restrict__ fbh, const unsigned short* __restrict__ fdh,
            const int* __restrict__ tb, const int* __restrict__ bb_arr,
            const int* __restrict__ mouth_word,
            const int* __restrict__ col_g, const int* __restrict__ col_gb,
            const int* __restrict__ col_gm, const int* __restrict__ col_gc,
            int Nb, int Nd, int D,
            float* __restrict__ rowsumA, float* __restrict__ numv,
            float* __restrict__ t1v, float* __restrict__ t3v) {
    __shared__ float cnum[64], ct1[64], ct3[64], rsum[64];

    int t = threadIdx.x, lane = t & 63, wid = t >> 6;
    int wr = wid >> 1, wc = wid & 1;
    int bm = blockIdx.x * 64, bn = blockIdx.y * 64;
    int l15 = lane & 15, lhi = lane >> 4;

    if (t < 64) { cnum[t] = 0.f; ct1[t] = 0.f; ct3[t] = 0.f; rsum[t] = 0.f; }

    f32x4 acc[2][2] = {};
    const unsigned short* ap = fbh + (size_t)(bm + wr * 32 + l15) * D + lhi * 8;
    const unsigned short* bp = fdh + (size_t)(bn + wc * 32 + l15) * D + lhi * 8;
    size_t rstep = (size_t)16 * D;

    #pragma unroll 8
    for (int k0 = 0; k0 < D; k0 += 32) {
        bf16x8 a0 = *(const bf16x8*)(ap + k0);
        bf16x8 a1 = *(const bf16x8*)(ap + rstep + k0);
        bf16x8 b0 = *(const bf16x8*)(bp + k0);
        bf16x8 b1 = *(const bf16x8*)(bp + rstep + k0);
        acc[0][0] = __builtin_amdgcn_mfma_f32_16x16x32_bf16(a0, b0, acc[0][0], 0, 0, 0);
        acc[0][1] = __builtin_amdgcn_mfma_f32_16x16x32_bf16(a0, b1, acc[0][1], 0, 0, 0);
        acc[1][0] = __builtin_amdgcn_mfma_f32_16x16x32_bf16(a1, b0, acc[1][0], 0, 0, 0);
        acc[1][1] = __builtin_amdgcn_mfma_f32_16x16x32_bf16(a1, b1, acc[1][1], 0, 0, 0);
    }

    // ---- epilogue ----
    // col meta: col = bn + wc*32 + nj*16 + l15
    int cgb[2], cgm[2], cgc[2];
    #pragma unroll
    for (int nj = 0; nj < 2; ++nj) {
        int col = bn + wc * 32 + nj * 16 + l15;
        cgb[nj] = col_gb[col]; cgm[nj] = col_gm[col]; cgc[nj] = col_gc[col];
    }

    float pnum[2] = {0.f, 0.f}, pt1[2] = {0.f, 0.f}, pt3[2] = {0.f, 0.f};
    float prow[2][4];

    #pragma unroll
    for (int mi = 0; mi < 2; ++mi) {
        #pragma unroll
        for (int r = 0; r < 4; ++r) {
            int i = bm + wr * 32 + mi * 16 + lhi * 4 + r;
            int tbi = tb[i], bbi = bb_arr[i];
            int mw = mouth_word[bbi];
            bool fg = (tbi != -1);
            float pr = 0.f;
            #pragma unroll
            for (int nj = 0; nj < 2; ++nj) {
                float e = __expf(acc[mi][nj][r] * INVT - CSHIFT);
                bool match = fg ? (cgc[nj] == mw) : ((cgb[nj] == bbi) && (cgm[nj] == 0));
                float a = (match && (bbi != cgb[nj])) ? 0.f : e;
                pnum[nj] += match ? e : 0.f;
                pt1[nj] += a;
                pt3[nj] += match ? a : 0.f;
                pr += a;
            }
            prow[mi][r] = pr;
        }
    }

    __syncthreads();   // LDS zero-init visible

    // col reduce: lanes sharing a col differ in lhi -> xor 16, 32
    #pragma unroll
    for (int nj = 0; nj < 2; ++nj) {
        float n = pnum[nj], x1 = pt1[nj], x3 = pt3[nj];
        n  += __shfl_xor(n, 16, 64);  n  += __shfl_xor(n, 32, 64);
        x1 += __shfl_xor(x1, 16, 64); x1 += __shfl_xor(x1, 32, 64);
        x3 += __shfl_xor(x3, 16, 64); x3 += __shfl_xor(x3, 32, 64);
        if (lhi == 0) {
            int c = wc * 32 + nj * 16 + l15;
            atomicAdd(&cnum[c], n); atomicAdd(&ct1[c], x1); atomicAdd(&ct3[c], x3);
        }
    }
    // row reduce: lanes sharing a row differ in l15 -> xor 1,2,4,8
    #pragma unroll
    for (int mi = 0; mi < 2; ++mi) {
        #pragma unroll
        for (int r = 0; r < 4; ++r) {
            float v = prow[mi][r];
            v += __shfl_xor(v, 1, 64); v += __shfl_xor(v, 2, 64);
            v += __shfl_xor(v, 4, 64); v += __shfl_xor(v, 8, 64);
            if (l15 == 0) atomicAdd(&rsum[wr * 32 + mi * 16 + lhi * 4 + r], v);
        }
    }
    __syncthreads();

    if (t < 16) {
        int base = bn + t * 4;
        int g0 = col_g[base];
        float sn = cnum[4*t] + cnum[4*t+1] + cnum[4*t+2] + cnum[4*t+3];
        float s1 = ct1[4*t] + ct1[4*t+1] + ct1[4*t+2] + ct1[4*t+3];
        float s3 = ct3[4*t] + ct3[4*t+1] + ct3[4*t+2] + ct3[4*t+3];
        if (col_g[base+1] == g0 && col_g[base+2] == g0 && col_g[base+3] == g0) {
            atomicAdd(&numv[g0], sn); atomicAdd(&t1v[g0], s1); atomicAdd(&t3v[g0], s3);
        } else {
            #pragma unroll
            for (int c = 0; c < 4; ++c) {
                int g = col_g[base + c];
                atomicAdd(&numv[g], cnum[4*t+c]);
                atomicAdd(&t1v[g], ct1[4*t+c]);
                atomicAdd(&t3v[g], ct3[4*t+c]);
            }
        }
    } else if (t >= 64 && t < 128) {
        int r = t - 64;
        atomicAdd(&rowsumA[bm + r], rsum[r]);
    }
}

// ---------------- kernel 3: t2 + final loss (single block) ----------------
__global__ void k_finish(const int* __restrict__ tb, const int* __restrict__ bb_arr,
                         const int* __restrict__ mouth_word, const int* __restrict__ ut,
                         const int* __restrict__ group_batch, const int* __restrict__ group_is_mouth,
                         const float* __restrict__ rowsumA,
                         const float* __restrict__ numv, const float* __restrict__ t1v,
                         const float* __restrict__ t3v,
                         int Nb, int G, float* __restrict__ out) {
    __shared__ float t2g[1024];
    __shared__ float bgs[1024];
    __shared__ float red[256];
    int t = threadIdx.x;
    for (int i = t; i < 1024; i += 256) { t2g[i] = 0.f; bgs[i] = 0.f; }
    __syncthreads();
    for (int i = t; i < Nb; i += 256) {
        float r = rowsumA[i];
        int tbi = tb[i], bbi = bb_arr[i] & 1023;
        if (tbi != -1) {
            int g = lower_bound_i(ut, G, mouth_word[bbi]);
            atomicAdd(&t2g[g & 1023], r);
        } else {
            atomicAdd(&bgs[bbi], r);
        }
    }
    __syncthreads();
    float acc = 0.f;
    for (int g = t; g < G; g += 256) {
        float t2 = t2g[g & 1023];
        int gb = group_batch[g];
        if (group_is_mouth[g] == 0 && gb >= 0 && gb < 1024) t2 += bgs[gb];
        float den = t1v[g] + t2 - t3v[g];
        acc += logf(den) - logf(numv[g]);
    }
    red[t] = acc;
    __syncthreads();
    for (int k = 128; k >= 1; k >>= 1) {
        if (t < k) red[t] += red[t + k];
        __syncthreads();
    }
    if (t == 0) out[0] = red[0] / (float)G;
}

extern "C" void kernel_launch(void* const* d_in, const int* in_sizes, int n_in,
                              void* d_out, int out_size, void* d_ws, size_t ws_size,
                              hipStream_t stream) {
    const float* fb = (const float*)d_in[0];
    const float* fd = (const float*)d_in[1];
    const int* tb = (const int*)d_in[2];
    const int* td = (const int*)d_in[3];
    const int* bb = (const int*)d_in[4];
    const int* bd = (const int*)d_in[5];
    const int* im = (const int*)d_in[6];
    const int* ut = (const int*)d_in[7];

    int Nb = in_sizes[2];
    int Nd = in_sizes[3];
    int G  = in_sizes[7];
    int D  = in_sizes[0] / Nb;
    float* out = (float*)d_out;

    // workspace layout
    char* p = (char*)d_ws;
    unsigned short* fbh = (unsigned short*)p; p += (size_t)Nb * D * sizeof(unsigned short);
    unsigned short* fdh = (unsigned short*)p; p += (size_t)Nd * D * sizeof(unsigned short);
    float* rowsumA = (float*)p; p += (size_t)Nb * sizeof(float);
    float* numv = (float*)p;    p += (size_t)G * sizeof(float);
    float* t1v = (float*)p;     p += (size_t)G * sizeof(float);
    float* t3v = (float*)p;     p += (size_t)G * sizeof(float);
    int* mouth_word = (int*)p;     p += (size_t)Nb * sizeof(int);
    int* group_batch = (int*)p;    p += (size_t)G * sizeof(int);
    int* group_is_mouth = (int*)p; p += (size_t)G * sizeof(int);
    int* col_g = (int*)p;  p += (size_t)Nd * sizeof(int);
    int* col_gb = (int*)p; p += (size_t)Nd * sizeof(int);
    int* col_gm = (int*)p; p += (size_t)Nd * sizeof(int);
    int* col_gc = (int*)p; p += (size_t)Nd * sizeof(int);

    {
        int waves = Nb + Nd;
        int blocks = (waves + 3) / 4;
        k_prep<<<blocks, 256, 0, stream>>>(fb, fd, Nb, Nd, D, fbh, fdh, rowsumA,
                                           td, bd, im, ut, G,
                                           mouth_word, group_batch, group_is_mouth,
                                           col_g, col_gb, col_gm, col_gc,
                                           numv, t1v, t3v);
    }

    dim3 grid(Nb / 64, Nd / 64);
    k_main<<<grid, 256, 0, stream>>>(fbh, fdh, tb, bb, mouth_word,
                                     col_g, col_gb, col_gm, col_gc,
                                     Nb, Nd, D, rowsumA, numv, t1v, t3v);

    k_finish<<<1, 256, 0, stream>>>(tb, bb, mouth_word, ut, group_batch, group_is_mouth,
                                    rowsumA, numv, t1v, t3v, Nb, G, out);
}